// Round 1
// baseline (2737.683 us; speedup 1.0000x reference)
//
#include <hip/hip_runtime.h>

#define Nn 16384
#define Ee 32768
#define NL (Nn * 32)

__device__ __forceinline__ float gelu_f(float x) {
    // exact (erf) gelu, matches jax.nn.gelu(approximate=False)
    return 0.5f * x * (1.0f + erff(x * 0.7071067811865476f));
}

__device__ __forceinline__ void atomic_add_f(float* p, float v) {
    __hip_atomic_fetch_add(p, v, __ATOMIC_RELAXED, __HIP_MEMORY_SCOPE_AGENT);
}

// ---------------- projector (+ zero agg & deg) ----------------
__global__ __launch_bounds__(64) void proj_kernel(
    const float* __restrict__ nodes, const float* __restrict__ grid2,
    const float* __restrict__ w1, const float* __restrict__ b1,
    const float* __restrict__ w2, const float* __restrict__ b2,
    float* __restrict__ x0, float* __restrict__ agg, float* __restrict__ deg)
{
    const int n = blockIdx.x * 64 + threadIdx.x;
    float in[12];
#pragma unroll
    for (int j = 0; j < 10; ++j) in[j] = nodes[n * 10 + j];
    in[10] = grid2[n * 2 + 0];
    in[11] = grid2[n * 2 + 1];
    float h[16];
#pragma unroll
    for (int j = 0; j < 16; ++j) {
        float a = b1[j];
#pragma unroll
        for (int i = 0; i < 12; ++i) a = fmaf(in[i], w1[i * 16 + j], a);
        h[j] = gelu_f(a);
    }
#pragma unroll
    for (int o = 0; o < 32; ++o) {
        float a = b2[o];
#pragma unroll
        for (int j = 0; j < 16; ++j) a = fmaf(h[j], w2[j * 32 + o], a);
        x0[n * 32 + o] = gelu_f(a);   // outer gelu per reference
        agg[n * 32 + o] = 0.0f;       // init accumulator for first layer
    }
#pragma unroll
    for (int s = 0; s < 7; ++s) deg[s * Nn + n] = 0.0f;
}

struct EPtrs { const int* p[7]; };

// ---------------- degree count (once, all 7 edge sets) ----------------
__global__ __launch_bounds__(256) void count_deg_kernel(EPtrs ei, float* __restrict__ deg)
{
    const int t = blockIdx.x * 256 + threadIdx.x;   // 7*Ee threads
    const int s = t >> 15;                          // Ee = 2^15
    const int e = t & (Ee - 1);
    const int dst = ei.p[s][Ee + e];
    atomic_add_f(&deg[s * Nn + dst], 1.0f);
}

// ---------------- per-edge kernel MLP + matvec + scatter ----------------
// block = 256 threads = 4 waves; lane -> edge (64 edges / block),
// wave w handles h in [w*16, w*16+16) -> weight addresses wave-uniform (s_load)
__global__ __launch_bounds__(256) void msg_scatter_kernel(
    const float* __restrict__ xa, const float* __restrict__ xb,
    const int* __restrict__ eidx, const float* __restrict__ eattr,
    const float* __restrict__ kw1, const float* __restrict__ kb1,
    const float* __restrict__ kw2, const float* __restrict__ kb2,
    float* __restrict__ agg)
{
    __shared__ float red[4 * 64 * 37];   // [wave][edge][o] pad 37 vs bank conflicts
    const int lane = threadIdx.x & 63;
    const int wv = __builtin_amdgcn_readfirstlane(threadIdx.x >> 6);
    const int e = blockIdx.x * 64 + lane;
    const int src = eidx[e];

    float xs[32];
#pragma unroll
    for (int i = 0; i < 32; i += 4) {
        float4 v = *reinterpret_cast<const float4*>(xa + (size_t)src * 32 + i);
        if (xb) {
            float4 u = *reinterpret_cast<const float4*>(xb + (size_t)src * 32 + i);
            v.x += u.x; v.y += u.y; v.z += u.z; v.w += u.w;
        }
        xs[i + 0] = v.x; xs[i + 1] = v.y; xs[i + 2] = v.z; xs[i + 3] = v.w;
    }
    float ea5[5];
#pragma unroll
    for (int j = 0; j < 5; ++j) ea5[j] = eattr[e * 5 + j];

    float msg[32];
#pragma unroll
    for (int o = 0; o < 32; ++o) msg[o] = 0.0f;

    // kb2 bias term: msg[o] += sum_i xs[i]*kb2[i*32+o]  (wave 0 only)
    if (wv == 0) {
#pragma unroll
        for (int i = 0; i < 32; ++i) {
            const float xi = xs[i];
#pragma unroll
            for (int o = 0; o < 32; ++o) msg[o] = fmaf(xi, kb2[i * 32 + o], msg[o]);
        }
    }

    const int h0 = wv * 16;
    for (int hl = 0; hl < 16; ++hl) {
        const int h = h0 + hl;
        float pre = kb1[h];
#pragma unroll
        for (int j = 0; j < 5; ++j) pre = fmaf(ea5[j], kw1[j * 64 + h], pre);
        const float Hh = gelu_f(pre);
        const float* __restrict__ W = kw2 + h * 1024;   // wave-uniform row
#pragma unroll
        for (int i = 0; i < 32; ++i) {
            const float t = Hh * xs[i];
#pragma unroll
            for (int o = 0; o < 32; ++o) msg[o] = fmaf(t, W[i * 32 + o], msg[o]);
        }
    }

    // reduce the 4 h-partials in LDS, then one atomic per (edge, o)
    float* myred = red + (wv * 64 + lane) * 37;
#pragma unroll
    for (int o = 0; o < 32; ++o) myred[o] = msg[o];
    __syncthreads();

    const int er = threadIdx.x & 63;
    const int og = threadIdx.x >> 6;
    const int dst = eidx[Ee + blockIdx.x * 64 + er];
    float* aggrow = agg + (size_t)dst * 32;
#pragma unroll
    for (int oo = 0; oo < 8; ++oo) {
        const int o = og * 8 + oo;
        float sum = red[(0 * 64 + er) * 37 + o] + red[(1 * 64 + er) * 37 + o]
                  + red[(2 * 64 + er) * 37 + o] + red[(3 * 64 + er) * 37 + o];
        atomic_add_f(aggrow + o, sum);
    }
}

// ---------------- node update: x' = gelu(x@lw + lb + agg*inv_deg), re-zero agg ----------------
__global__ __launch_bounds__(64) void node_update_kernel(
    const float* __restrict__ xa, const float* __restrict__ xb,
    float* __restrict__ xout, float* __restrict__ agg,
    const float* __restrict__ deg,
    const float* __restrict__ lw, const float* __restrict__ lb)
{
    const int n = blockIdx.x * 64 + threadIdx.x;
    float row[32];
#pragma unroll
    for (int i = 0; i < 32; i += 4) {
        float4 v = *reinterpret_cast<const float4*>(xa + (size_t)n * 32 + i);
        if (xb) {
            float4 u = *reinterpret_cast<const float4*>(xb + (size_t)n * 32 + i);
            v.x += u.x; v.y += u.y; v.z += u.z; v.w += u.w;
        }
        row[i + 0] = v.x; row[i + 1] = v.y; row[i + 2] = v.z; row[i + 3] = v.w;
    }
    const float d = deg[n];
    const float inv = d > 0.0f ? 1.0f / d : 0.0f;
    float acc[32];
#pragma unroll
    for (int o = 0; o < 32; ++o) acc[o] = fmaf(agg[n * 32 + o], inv, lb[o]);
#pragma unroll
    for (int i = 0; i < 32; ++i) {
        const float xi = row[i];
#pragma unroll
        for (int o = 0; o < 32; ++o) acc[o] = fmaf(xi, lw[i * 32 + o], acc[o]);
    }
#pragma unroll
    for (int o = 0; o < 32; ++o) {
        xout[(size_t)n * 32 + o] = gelu_f(acc[o]);
        agg[(size_t)n * 32 + o] = 0.0f;   // ready for next layer's scatter
    }
}

// ---------------- decoder: out = gelu((n11+n21)@dw1+db1)@dw2+db2 ----------------
__global__ __launch_bounds__(64) void decode_kernel(
    const float* __restrict__ a, const float* __restrict__ b,
    const float* __restrict__ w1, const float* __restrict__ b1,
    const float* __restrict__ w2, const float* __restrict__ b2,
    float* __restrict__ out)
{
    const int n = blockIdx.x * 64 + threadIdx.x;
    float s[32];
#pragma unroll
    for (int i = 0; i < 32; ++i) s[i] = a[n * 32 + i] + b[n * 32 + i];
    float acc = b2[0];
#pragma unroll
    for (int j = 0; j < 16; ++j) {
        float h = b1[j];
#pragma unroll
        for (int i = 0; i < 32; ++i) h = fmaf(s[i], w1[i * 16 + j], h);
        acc = fmaf(gelu_f(h), w2[j], acc);
    }
    out[n] = acc;
}

extern "C" void kernel_launch(void* const* d_in, const int* in_sizes, int n_in,
                              void* d_out, int out_size, void* d_ws, size_t ws_size,
                              hipStream_t stream)
{
    const float* nodes = (const float*)d_in[0];
    const float* grid2 = (const float*)d_in[1];
    const int* ei[7];
    const float* ea[7];
    for (int s = 0; s < 7; ++s) {
        ei[s] = (const int*)d_in[2 + s];
        ea[s] = (const float*)d_in[9 + s];
    }
    const float* pw1 = (const float*)d_in[18];
    const float* pb1 = (const float*)d_in[19];
    const float* pw2 = (const float*)d_in[20];
    const float* pb2 = (const float*)d_in[21];
    const float* dw1 = (const float*)d_in[22];
    const float* db1 = (const float*)d_in[23];
    const float* dw2 = (const float*)d_in[24];
    const float* db2 = (const float*)d_in[25];
    const float* kw1 = (const float*)d_in[26];
    const float* kb1 = (const float*)d_in[27];
    const float* kw2 = (const float*)d_in[28];
    const float* kb2 = (const float*)d_in[29];
    const float* lw  = (const float*)d_in[30];
    const float* lb  = (const float*)d_in[31];

    float* ws  = (float*)d_ws;
    float* x0  = ws + 0 * (size_t)NL;
    float* n11 = ws + 1 * (size_t)NL;
    float* n12 = ws + 2 * (size_t)NL;
    float* n22 = ws + 3 * (size_t)NL;
    float* n23 = ws + 4 * (size_t)NL;
    float* n33 = ws + 5 * (size_t)NL;
    float* n32 = ws + 6 * (size_t)NL;
    float* n21 = ws + 7 * (size_t)NL;
    float* agg = ws + 8 * (size_t)NL;
    float* deg = ws + 9 * (size_t)NL;   // 7*Nn floats

    proj_kernel<<<Nn / 64, 64, 0, stream>>>(nodes, grid2, pw1, pb1, pw2, pb2, x0, agg, deg);

    EPtrs ep;
    for (int s = 0; s < 7; ++s) ep.p[s] = ei[s];
    count_deg_kernel<<<7 * Ee / 256, 256, 0, stream>>>(ep, deg);

    auto layer = [&](int i, int d, int s, const float* xa, const float* xb, float* xo) {
        const int id = i * 2 + d;
        msg_scatter_kernel<<<Ee / 64, 256, 0, stream>>>(
            xa, xb, ei[s], ea[s],
            kw1 + (size_t)id * 320, kb1 + (size_t)id * 64,
            kw2 + (size_t)id * 65536, kb2 + (size_t)id * 1024, agg);
        node_update_kernel<<<Nn / 64, 64, 0, stream>>>(
            xa, xb, xo, agg, deg + (size_t)s * Nn,
            lw + (size_t)id * 1024, lb + (size_t)id * 32);
    };
    auto gno_block = [&](int i, int s, const float* xa, const float* xb, float* xo) {
        layer(i, 0, s, xa, xb, xo);
        layer(i, 1, s, xo, nullptr, xo);
    };

    // block param index order: n11->0, n12->3, n22->1, n23->4, n33->2, n32->5, n21->6
    gno_block(0, 0, x0,  nullptr, n11);
    gno_block(3, 1, x0,  nullptr, n12);
    gno_block(1, 2, n12, nullptr, n22);
    gno_block(4, 3, n12, nullptr, n23);
    gno_block(2, 4, n23, nullptr, n33);
    gno_block(5, 5, n33, nullptr, n32);
    gno_block(6, 6, n32, n22,     n21);

    decode_kernel<<<Nn / 64, 64, 0, stream>>>(n11, n21, dw1, db1, dw2, db2, (float*)d_out);
}

// Round 2
// 1136.085 us; speedup vs baseline: 2.4098x; 2.4098x over previous
//
#include <hip/hip_runtime.h>

#define Nn 16384
#define Ee 32768
#define NL (Nn * 32)

typedef _Float16 hf16;
typedef _Float16 half8 __attribute__((ext_vector_type(8)));
typedef float f32x16 __attribute__((ext_vector_type(16)));

__device__ __forceinline__ float gelu_f(float x) {
    return 0.5f * x * (1.0f + erff(x * 0.7071067811865476f));
}

__device__ __forceinline__ void atomic_add_f(float* p, float v) {
    __hip_atomic_fetch_add(p, v, __ATOMIC_RELAXED, __HIP_MEMORY_SCOPE_AGENT);
}

__device__ __forceinline__ f32x16 zero16() {
    f32x16 v;
#pragma unroll
    for (int r = 0; r < 16; ++r) v[r] = 0.0f;
    return v;
}

// ---------------- projector (+ zero agg & deg), thread = node ----------------
__global__ __launch_bounds__(256) void proj_kernel(
    const float* __restrict__ nodes, const float* __restrict__ grid2,
    const float* __restrict__ w1, const float* __restrict__ b1,
    const float* __restrict__ w2, const float* __restrict__ b2,
    float* __restrict__ x0, float* __restrict__ agg, float* __restrict__ deg)
{
    const int n = blockIdx.x * 256 + threadIdx.x;
    float in[12];
#pragma unroll
    for (int j = 0; j < 10; ++j) in[j] = nodes[n * 10 + j];
    in[10] = grid2[n * 2 + 0];
    in[11] = grid2[n * 2 + 1];
    float h[16];
#pragma unroll
    for (int j = 0; j < 16; ++j) {
        float a = b1[j];
#pragma unroll
        for (int i = 0; i < 12; ++i) a = fmaf(in[i], w1[i * 16 + j], a);
        h[j] = gelu_f(a);
    }
#pragma unroll
    for (int o = 0; o < 32; ++o) {
        float a = b2[o];
#pragma unroll
        for (int j = 0; j < 16; ++j) a = fmaf(h[j], w2[j * 32 + o], a);
        x0[(size_t)n * 32 + o] = gelu_f(a);
        agg[(size_t)n * 32 + o] = 0.0f;
    }
#pragma unroll
    for (int s = 0; s < 7; ++s) deg[s * Nn + n] = 0.0f;
}

struct EPtrs { const int* p[7]; };

// ---------------- degree count (once, all 7 edge sets) ----------------
__global__ __launch_bounds__(256) void count_deg_kernel(EPtrs ei, float* __restrict__ deg)
{
    const int t = blockIdx.x * 256 + threadIdx.x;
    const int s = t >> 15;
    const int e = t & (Ee - 1);
    const int dst = ei.p[s][Ee + e];
    atomic_add_f(&deg[s * Nn + dst], 1.0f);
}

// ---------------- W pre-pack into B-fragment lane order ----------------
// B-frag for mfma_f32_32x32x16_f16: lane l holds col n = l&31, k = 16*ks + 8*(l>>5) + j.
// Wpack layout: [id(14)][nt(32)][ks(4)][p(2)] frags of 512 halves (lane*8 + j).
// W_perm[k][n] with n = o*32+i equals kw2[k][i*32+o].
__global__ __launch_bounds__(256) void wprep_kernel(const float* __restrict__ kw2,
                                                    hf16* __restrict__ Wpack)
{
    const int id = blockIdx.x >> 6;   // 14
    const int k  = blockIdx.x & 63;   // h
    const float* row = kw2 + (size_t)id * 65536 + (size_t)k * 1024;
    const int ks = k >> 4, kh = (k & 15) >> 3, j = k & 7;
#pragma unroll
    for (int c = 0; c < 4; ++c) {
        const int m = threadIdx.x * 4 + c;      // i*32+o
        const float v = row[m];
        const int i = m >> 5, o = m & 31;
        const int lane = i + (kh << 5);
        const hf16 vh = (hf16)v;
        const hf16 vl = (hf16)((v - (float)vh) * 1024.0f);
        const size_t base = ((((size_t)id * 32 + o) * 4 + ks) * 2);
        Wpack[(base + 0) * 512 + lane * 8 + j] = vh;
        Wpack[(base + 1) * 512 + lane * 8 + j] = vl;
    }
}

// ---------------- fused: edge MLP (H) + MFMA GEMM (k') + per-edge dot + scatter --------
// grid = (Ee/64)*2; block 256 = 4 waves. blockIdx: eblk = bx>>1 (64 edges), half = bx&1.
// wave w covers n-tiles nt = half*16 + w*4 + t, t in [0,4); o == nt, i == lane&31.
__global__ __launch_bounds__(256, 2) void gemm_scatter_kernel(
    const float* __restrict__ xa, const float* __restrict__ xb,
    const int* __restrict__ eidx, const float* __restrict__ eattr,
    const float* __restrict__ kw1l, const float* __restrict__ kb1l,
    const hf16* __restrict__ WpackL, const float* __restrict__ kb2l,
    float* __restrict__ agg)
{
    __shared__ hf16 aLDSh[8192];                    // A frags: [mt2][ks4][p2][lane64][8]
    __shared__ __align__(16) float sTile[4 * 1024]; // per-wave 32x32 transpose scratch

    const int eblk = blockIdx.x >> 1;
    const int half = blockIdx.x & 1;
    const int t = threadIdx.x;
    const int l = t & 63;
    const int wv = t >> 6;

    // ---- phase 0: H = gelu(eattr @ kw1 + kb1), split f16 hi/lo into A-frag LDS ----
    {
        const int e_loc = t >> 2;      // 0..63
        const int hq = t & 3;          // ks
        const int eg = eblk * 64 + e_loc;
        float ea5[5];
#pragma unroll
        for (int j = 0; j < 5; ++j) ea5[j] = eattr[(size_t)eg * 5 + j];
        const int mt = e_loc >> 5;
#pragma unroll
        for (int hh = 0; hh < 16; ++hh) {
            const int h = hq * 16 + hh;
            float pre = kb1l[h];
#pragma unroll
            for (int j = 0; j < 5; ++j) pre = fmaf(ea5[j], kw1l[j * 64 + h], pre);
            const float H = gelu_f(pre);
            const hf16 vh = (hf16)H;
            const hf16 vl = (hf16)((H - (float)vh) * 1024.0f);
            const int lane = (e_loc & 31) + ((hh >> 3) << 5);
            const int fi = (mt * 4 + hq) * 2;
            aLDSh[(fi + 0) * 512 + lane * 8 + (hh & 7)] = vh;
            aLDSh[(fi + 1) * 512 + lane * 8 + (hh & 7)] = vl;
        }
    }

    // ---- gather xs in stage-B layout: lane l -> edge (l&31) of each mtile, i-range (l>>5)*16 ----
    int sidx[2], dstv[2];
    float xsr[2][16];
    const int i0 = (l >> 5) * 16;
#pragma unroll
    for (int mt = 0; mt < 2; ++mt) {
        const int eg2 = eblk * 64 + mt * 32 + (l & 31);
        sidx[mt] = eidx[eg2];
        dstv[mt] = eidx[Ee + eg2];
        const float* xr = xa + (size_t)sidx[mt] * 32 + i0;
#pragma unroll
        for (int c = 0; c < 4; ++c) {
            float4 v = *reinterpret_cast<const float4*>(xr + c * 4);
            if (xb) {
                const float* xr2 = xb + (size_t)sidx[mt] * 32 + i0;
                float4 u = *reinterpret_cast<const float4*>(xr2 + c * 4);
                v.x += u.x; v.y += u.y; v.z += u.z; v.w += u.w;
            }
            xsr[mt][c * 4 + 0] = v.x; xsr[mt][c * 4 + 1] = v.y;
            xsr[mt][c * 4 + 2] = v.z; xsr[mt][c * 4 + 3] = v.w;
        }
    }

    __syncthreads();

    // ---- load A fragments (16 x ds_read_b128) ----
    half8 Ah[2][4], Al[2][4];
    const half8* a8 = (const half8*)aLDSh;
#pragma unroll
    for (int mt = 0; mt < 2; ++mt)
#pragma unroll
        for (int ks = 0; ks < 4; ++ks) {
            Ah[mt][ks] = a8[((mt * 4 + ks) * 2 + 0) * 64 + l];
            Al[mt][ks] = a8[((mt * 4 + ks) * 2 + 1) * 64 + l];
        }

    float* sW = sTile + wv * 1024;
    const float4* s4 = (const float4*)sW;
    const int col = l & 31;
    const int eh = col & 7;   // swizzle key for reads (row = col here)

    // ---- main loop over this wave's 4 n-tiles ----
    for (int tt = 0; tt < 4; ++tt) {
        const int nt = half * 16 + wv * 4 + tt;   // == o
        const half8* bp = (const half8*)(WpackL + ((size_t)nt * 8) * 512);
        half8 Bh[4], Bl[4];
#pragma unroll
        for (int ks = 0; ks < 4; ++ks) {
            Bh[ks] = bp[(ks * 2 + 0) * 64 + l];
            Bl[ks] = bp[(ks * 2 + 1) * 64 + l];
        }

        f32x16 ah[2], ax[2];
        ah[0] = zero16(); ah[1] = zero16(); ax[0] = zero16(); ax[1] = zero16();
#pragma unroll
        for (int mt = 0; mt < 2; ++mt)
#pragma unroll
            for (int ks = 0; ks < 4; ++ks) {
                ah[mt] = __builtin_amdgcn_mfma_f32_32x32x16_f16(Ah[mt][ks], Bh[ks], ah[mt], 0, 0, 0);
                ax[mt] = __builtin_amdgcn_mfma_f32_32x32x16_f16(Al[mt][ks], Bh[ks], ax[mt], 0, 0, 0);
                ax[mt] = __builtin_amdgcn_mfma_f32_32x32x16_f16(Ah[mt][ks], Bl[ks], ax[mt], 0, 0, 0);
            }

        const float kb2v = kb2l[col * 32 + nt];   // kb2[i, o]

#pragma unroll
        for (int mt = 0; mt < 2; ++mt) {
            // write C tile (k' + kb2) to swizzled per-wave LDS: element (row=edge, col=i)
#pragma unroll
            for (int r = 0; r < 16; ++r) {
                const int row = (r & 3) + 8 * (r >> 2) + 4 * (l >> 5);
                const float val = fmaf(ax[mt][r], 9.765625e-4f, ah[mt][r]) + kb2v;
                sW[row * 32 + (((col >> 2) ^ (row & 7)) << 2) + (col & 3)] = val;
            }
            // read back: lane l -> edge row (l&31), i-range (l>>5)*16
            float p = 0.0f;
#pragma unroll
            for (int cc = 0; cc < 4; ++cc) {
                const int c = (l >> 5) * 4 + cc;
                const float4 ch = s4[(l & 31) * 8 + (c ^ eh)];
                p = fmaf(ch.x, xsr[mt][cc * 4 + 0], p);
                p = fmaf(ch.y, xsr[mt][cc * 4 + 1], p);
                p = fmaf(ch.z, xsr[mt][cc * 4 + 2], p);
                p = fmaf(ch.w, xsr[mt][cc * 4 + 3], p);
            }
            p += __shfl_xor(p, 32);
            if (l < 32) atomic_add_f(&agg[(size_t)dstv[mt] * 32 + nt], p);
        }
    }
}

// ---------------- node update: x' = gelu(x@lw + lb + agg*inv_deg), re-zero agg --------
// thread = (node, o-quad of 8); grid = Nn*4/256
__global__ __launch_bounds__(256) void node_update_kernel(
    const float* __restrict__ xa, const float* __restrict__ xb,
    float* __restrict__ xout, float* __restrict__ agg,
    const float* __restrict__ deg,
    const float* __restrict__ lw, const float* __restrict__ lb)
{
    __shared__ float lwS[1024];
#pragma unroll
    for (int c = 0; c < 4; ++c) lwS[threadIdx.x + 256 * c] = lw[threadIdx.x + 256 * c];
    __syncthreads();

    const int g = blockIdx.x * 256 + threadIdx.x;
    const int n = g >> 2;
    const int q = g & 3;

    float row[32];
#pragma unroll
    for (int i = 0; i < 32; i += 4) {
        float4 v = *reinterpret_cast<const float4*>(xa + (size_t)n * 32 + i);
        if (xb) {
            float4 u = *reinterpret_cast<const float4*>(xb + (size_t)n * 32 + i);
            v.x += u.x; v.y += u.y; v.z += u.z; v.w += u.w;
        }
        row[i + 0] = v.x; row[i + 1] = v.y; row[i + 2] = v.z; row[i + 3] = v.w;
    }
    const float d = deg[n];
    const float inv = d > 0.0f ? 1.0f / d : 0.0f;
    float acc[8];
#pragma unroll
    for (int oo = 0; oo < 8; ++oo) {
        const int o = q * 8 + oo;
        acc[oo] = fmaf(agg[(size_t)n * 32 + o], inv, lb[o]);
    }
#pragma unroll
    for (int i = 0; i < 32; ++i) {
        const float xi = row[i];
#pragma unroll
        for (int oo = 0; oo < 8; ++oo) acc[oo] = fmaf(xi, lwS[i * 32 + q * 8 + oo], acc[oo]);
    }
#pragma unroll
    for (int oo = 0; oo < 8; ++oo) {
        const int o = q * 8 + oo;
        xout[(size_t)n * 32 + o] = gelu_f(acc[oo]);
        agg[(size_t)n * 32 + o] = 0.0f;
    }
}

// ---------------- decoder ----------------
__global__ __launch_bounds__(256) void decode_kernel(
    const float* __restrict__ a, const float* __restrict__ b,
    const float* __restrict__ w1, const float* __restrict__ b1,
    const float* __restrict__ w2, const float* __restrict__ b2,
    float* __restrict__ out)
{
    const int n = blockIdx.x * 256 + threadIdx.x;
    float s[32];
#pragma unroll
    for (int i = 0; i < 32; ++i) s[i] = a[(size_t)n * 32 + i] + b[(size_t)n * 32 + i];
    float acc = b2[0];
#pragma unroll
    for (int j = 0; j < 16; ++j) {
        float h = b1[j];
#pragma unroll
        for (int i = 0; i < 32; ++i) h = fmaf(s[i], w1[i * 16 + j], h);
        acc = fmaf(gelu_f(h), w2[j], acc);
    }
    out[n] = acc;
}

extern "C" void kernel_launch(void* const* d_in, const int* in_sizes, int n_in,
                              void* d_out, int out_size, void* d_ws, size_t ws_size,
                              hipStream_t stream)
{
    const float* nodes = (const float*)d_in[0];
    const float* grid2 = (const float*)d_in[1];
    const int* ei[7];
    const float* ea[7];
    for (int s = 0; s < 7; ++s) {
        ei[s] = (const int*)d_in[2 + s];
        ea[s] = (const float*)d_in[9 + s];
    }
    const float* pw1 = (const float*)d_in[18];
    const float* pb1 = (const float*)d_in[19];
    const float* pw2 = (const float*)d_in[20];
    const float* pb2 = (const float*)d_in[21];
    const float* dw1 = (const float*)d_in[22];
    const float* db1 = (const float*)d_in[23];
    const float* dw2 = (const float*)d_in[24];
    const float* db2 = (const float*)d_in[25];
    const float* kw1 = (const float*)d_in[26];
    const float* kb1 = (const float*)d_in[27];
    const float* kw2 = (const float*)d_in[28];
    const float* kb2 = (const float*)d_in[29];
    const float* lw  = (const float*)d_in[30];
    const float* lb  = (const float*)d_in[31];

    float* ws  = (float*)d_ws;
    float* x0  = ws + 0 * (size_t)NL;
    float* n11 = ws + 1 * (size_t)NL;
    float* n12 = ws + 2 * (size_t)NL;
    float* n22 = ws + 3 * (size_t)NL;
    float* n23 = ws + 4 * (size_t)NL;
    float* n33 = ws + 5 * (size_t)NL;
    float* n32 = ws + 6 * (size_t)NL;
    float* n21 = ws + 7 * (size_t)NL;
    float* agg = ws + 8 * (size_t)NL;
    float* deg = ws + 9 * (size_t)NL;                 // 7*Nn floats
    hf16* Wpack = (hf16*)(ws + 9 * (size_t)NL + 7 * (size_t)Nn);  // 14*32*4*2*512 halves

    proj_kernel<<<Nn / 256, 256, 0, stream>>>(nodes, grid2, pw1, pb1, pw2, pb2, x0, agg, deg);

    EPtrs ep;
    for (int s = 0; s < 7; ++s) ep.p[s] = ei[s];
    count_deg_kernel<<<7 * Ee / 256, 256, 0, stream>>>(ep, deg);

    wprep_kernel<<<14 * 64, 256, 0, stream>>>(kw2, Wpack);

    auto layer = [&](int i, int d, int s, const float* xa, const float* xb, float* xo) {
        const int id = i * 2 + d;
        gemm_scatter_kernel<<<(Ee / 64) * 2, 256, 0, stream>>>(
            xa, xb, ei[s], ea[s],
            kw1 + (size_t)id * 320, kb1 + (size_t)id * 64,
            Wpack + (size_t)id * 32 * 8 * 512, kb2 + (size_t)id * 1024, agg);
        node_update_kernel<<<Nn * 4 / 256, 256, 0, stream>>>(
            xa, xb, xo, agg, deg + (size_t)s * Nn,
            lw + (size_t)id * 1024, lb + (size_t)id * 32);
    };
    auto gno_block = [&](int i, int s, const float* xa, const float* xb, float* xo) {
        layer(i, 0, s, xa, xb, xo);
        layer(i, 1, s, xo, nullptr, xo);
    };

    // block param index order: n11->0, n12->3, n22->1, n23->4, n33->2, n32->5, n21->6
    gno_block(0, 0, x0,  nullptr, n11);
    gno_block(3, 1, x0,  nullptr, n12);
    gno_block(1, 2, n12, nullptr, n22);
    gno_block(4, 3, n12, nullptr, n23);
    gno_block(2, 4, n23, nullptr, n33);
    gno_block(5, 5, n33, nullptr, n32);
    gno_block(6, 6, n32, n22,     n21);

    decode_kernel<<<Nn / 256, 256, 0, stream>>>(n11, n21, dw1, db1, dw2, db2, (float*)d_out);
}

// Round 3
// 557.622 us; speedup vs baseline: 4.9096x; 2.0374x over previous
//
#include <hip/hip_runtime.h>

#define Nn 16384
#define Ee 32768
#define NL (Nn * 32)

typedef _Float16 hf16;
typedef _Float16 half8 __attribute__((ext_vector_type(8)));
typedef float f32x16 __attribute__((ext_vector_type(16)));

__device__ __forceinline__ float gelu_f(float x) {
    return 0.5f * x * (1.0f + erff(x * 0.7071067811865476f));
}

__device__ __forceinline__ f32x16 zero16() {
    f32x16 v;
#pragma unroll
    for (int r = 0; r < 16; ++r) v[r] = 0.0f;
    return v;
}

// ---------------- projector (+ zero deg/cursor), thread = node ----------------
__global__ __launch_bounds__(256) void proj_kernel(
    const float* __restrict__ nodes, const float* __restrict__ grid2,
    const float* __restrict__ w1, const float* __restrict__ b1,
    const float* __restrict__ w2, const float* __restrict__ b2,
    float* __restrict__ x0, int* __restrict__ deg_i, int* __restrict__ cursor)
{
    const int n = blockIdx.x * 256 + threadIdx.x;
    float in[12];
#pragma unroll
    for (int j = 0; j < 10; ++j) in[j] = nodes[n * 10 + j];
    in[10] = grid2[n * 2 + 0];
    in[11] = grid2[n * 2 + 1];
    float h[16];
#pragma unroll
    for (int j = 0; j < 16; ++j) {
        float a = b1[j];
#pragma unroll
        for (int i = 0; i < 12; ++i) a = fmaf(in[i], w1[i * 16 + j], a);
        h[j] = gelu_f(a);
    }
#pragma unroll
    for (int o = 0; o < 32; ++o) {
        float a = b2[o];
#pragma unroll
        for (int j = 0; j < 16; ++j) a = fmaf(h[j], w2[j * 32 + o], a);
        x0[(size_t)n * 32 + o] = gelu_f(a);
    }
#pragma unroll
    for (int s = 0; s < 7; ++s) { deg_i[s * Nn + n] = 0; cursor[s * Nn + n] = 0; }
}

struct EPtrs { const int* p[7]; };

// ---------------- degree count (int) ----------------
__global__ __launch_bounds__(256) void count_deg_kernel(EPtrs ei, int* __restrict__ deg_i)
{
    const int t = blockIdx.x * 256 + threadIdx.x;
    const int s = t >> 15;
    const int e = t & (Ee - 1);
    const int dst = ei.p[s][Ee + e];
    atomicAdd(&deg_i[s * Nn + dst], 1);
}

// ---------------- exclusive scan per edge set -> CSR offsets ----------------
__global__ __launch_bounds__(256) void scan_kernel(const int* __restrict__ deg_i,
                                                   int* __restrict__ off)
{
    const int s = blockIdx.x;
    const int t = threadIdx.x;
    const int* d = deg_i + (size_t)s * Nn;
    int* o = off + (size_t)s * (Nn + 1);
    int local[64];
    int sum = 0;
#pragma unroll
    for (int j = 0; j < 64; ++j) { local[j] = d[t * 64 + j]; sum += local[j]; }
    __shared__ int ps[256];
    ps[t] = sum;
    __syncthreads();
    for (int st = 1; st < 256; st <<= 1) {
        int v = (t >= st) ? ps[t - st] : 0;
        __syncthreads();
        ps[t] += v;
        __syncthreads();
    }
    int base = (t > 0) ? ps[t - 1] : 0;
#pragma unroll
    for (int j = 0; j < 64; ++j) { o[t * 64 + j] = base; base += local[j]; }
    if (t == 255) o[Nn] = base;   // == Ee
}

// ---------------- rank assignment (counting sort positions) ----------------
__global__ __launch_bounds__(256) void rank_kernel(EPtrs ei, const int* __restrict__ off,
                                                   int* __restrict__ cursor,
                                                   int* __restrict__ rank)
{
    const int t = blockIdx.x * 256 + threadIdx.x;
    const int s = t >> 15;
    const int e = t & (Ee - 1);
    const int dst = ei.p[s][Ee + e];
    const int r = off[(size_t)s * (Nn + 1) + dst] + atomicAdd(&cursor[s * Nn + dst], 1);
    rank[(size_t)s * Ee + e] = r;
}

// ---------------- W pre-pack into A-fragment lane order (+ kb2 aug channel) ----------
// A-frag (32x32x16 f16): lane l -> row m = l&31 (= i), k = ks*16 + 8*(l>>5) + j.
// value = kw2[k][(l&31)*32 + nt]; ks==4 is the augmented channel: k==64 -> kb2[(l&31)*32+nt].
// Wpack layout: [id(14)][nt(32)][ks(5)][p(2)][lane(64)][j(8)] halves.
__global__ __launch_bounds__(320) void wprep_kernel(const float* __restrict__ kw2,
                                                    const float* __restrict__ kb2,
                                                    hf16* __restrict__ Wpack)
{
    const int id = blockIdx.x >> 5;
    const int nt = blockIdx.x & 31;
    const int t = threadIdx.x;             // 320 = 5 ks * 64 lanes
    const int ks = t >> 6, lane = t & 63;
    const float* kw2l = kw2 + (size_t)id * 65536;
    const float* kb2l = kb2 + (size_t)id * 1024;
    half8 vh, vl;
#pragma unroll
    for (int j = 0; j < 8; ++j) {
        const int k = ks * 16 + (lane >> 5) * 8 + j;
        float v = 0.0f;
        if (ks < 4) v = kw2l[(size_t)k * 1024 + (lane & 31) * 32 + nt];
        else if (k == 64) v = kb2l[(lane & 31) * 32 + nt];
        const hf16 h = (hf16)v;
        vh[j] = h;
        vl[j] = (hf16)((v - (float)h) * 1024.0f);
    }
    half8* dst = (half8*)(Wpack + ((size_t)(id * 32 + nt) * 10 + ks * 2) * 512);
    dst[0 * 64 + lane] = vh;
    dst[1 * 64 + lane] = vl;
}

// ---------------- fused: edge MLP (H) + MFMA (W x H) + in-reg dot + rank store -------
// block = 256 thr = 4 waves, 128 edges (wave w owns edge tile mt=w), nt half-split:
// all waves iterate the SAME 16 n-tiles (W reads L1-broadcast across waves).
__global__ __launch_bounds__(256, 2) void gemm_kernel(
    const float* __restrict__ xa, const float* __restrict__ xb,
    const int* __restrict__ esrc, const int* __restrict__ erank,
    const float* __restrict__ eattr,
    const float* __restrict__ kw1l, const float* __restrict__ kb1l,
    const hf16* __restrict__ WpackL,
    float* __restrict__ msgS)
{
    __shared__ __align__(16) hf16 hLDS[4 * 5 * 2 * 512];   // 40 KiB: [mt][ks][p][lane][j]
    const int eblk = blockIdx.x >> 1;
    const int hf = blockIdx.x & 1;
    const int t = threadIdx.x, l = t & 63, wv = t >> 6;
    half8* hp8 = (half8*)hLDS;

    // ---- phase 0: H = gelu(eattr @ kw1 + kb1) (+aug channel), split hi/lo -> frag LDS ----
    {
        const int e_loc = t >> 1;          // 0..127
        const int hpart = t & 1;           // h in [hpart*32, hpart*32+32)
        const int mt = e_loc >> 5, colbase = e_loc & 31;
        const int eg = eblk * 128 + e_loc;
        float ea5[5];
#pragma unroll
        for (int j = 0; j < 5; ++j) ea5[j] = eattr[(size_t)eg * 5 + j];
        half8 vh[2][2], vl[2][2];
#pragma unroll
        for (int hh = 0; hh < 32; ++hh) {
            const int h = hpart * 32 + hh;
            float pre = kb1l[h];
#pragma unroll
            for (int j = 0; j < 5; ++j) pre = fmaf(ea5[j], kw1l[j * 64 + h], pre);
            const float H = gelu_f(pre);
            const hf16 hv = (hf16)H;
            vh[hh >> 4][(hh >> 3) & 1][hh & 7] = hv;
            vl[hh >> 4][(hh >> 3) & 1][hh & 7] = (hf16)((H - (float)hv) * 1024.0f);
        }
#pragma unroll
        for (int ksl = 0; ksl < 2; ++ksl)
#pragma unroll
            for (int kh = 0; kh < 2; ++kh) {
                const int f = (mt * 5 + hpart * 2 + ksl) * 2;
                hp8[f * 64 + colbase + kh * 32] = vh[ksl][kh];
                hp8[(f + 1) * 64 + colbase + kh * 32] = vl[ksl][kh];
            }
        if (hpart == 0) {
            half8 oneV, zV;
#pragma unroll
            for (int j = 0; j < 8; ++j) { oneV[j] = (hf16)0.0f; zV[j] = (hf16)0.0f; }
            oneV[0] = (hf16)1.0f;
            const int f4 = (mt * 5 + 4) * 2;
            hp8[f4 * 64 + colbase] = oneV;
            hp8[f4 * 64 + colbase + 32] = zV;
            hp8[(f4 + 1) * 64 + colbase] = zV;
            hp8[(f4 + 1) * 64 + colbase + 32] = zV;
        }
    }

    // ---- gather xs in C-layout order: lane l -> edge (l&31) of tile wv, i = (r&3)+8*(r>>2)+4*hi ----
    const int hi = l >> 5;
    const int el = eblk * 128 + wv * 32 + (l & 31);
    const int src = esrc[el];
    const int rk = erank[el];
    float xsr[16];
#pragma unroll
    for (int c = 0; c < 4; ++c) {
        float4 v = *reinterpret_cast<const float4*>(xa + (size_t)src * 32 + c * 8 + hi * 4);
        if (xb) {
            float4 u = *reinterpret_cast<const float4*>(xb + (size_t)src * 32 + c * 8 + hi * 4);
            v.x += u.x; v.y += u.y; v.z += u.z; v.w += u.w;
        }
        xsr[c * 4 + 0] = v.x; xsr[c * 4 + 1] = v.y;
        xsr[c * 4 + 2] = v.z; xsr[c * 4 + 3] = v.w;
    }

    __syncthreads();

    // ---- H fragments held in registers for this wave's edge tile ----
    half8 Hh[5], Hl[5];
#pragma unroll
    for (int ks = 0; ks < 5; ++ks) {
        Hh[ks] = hp8[((wv * 5 + ks) * 2 + 0) * 64 + l];
        Hl[ks] = hp8[((wv * 5 + ks) * 2 + 1) * 64 + l];
    }

    float4 p4;
    const hf16* wbase = WpackL + (size_t)hf * 16 * 5120;

#define LOADW(TT, WH, WL) { \
    const half8* wp = (const half8*)(wbase + (size_t)(TT) * 5120); \
    _Pragma("unroll") for (int ks = 0; ks < 5; ++ks) { \
        WH[ks] = wp[(ks * 2 + 0) * 64 + l]; \
        WL[ks] = wp[(ks * 2 + 1) * 64 + l]; } }

#define COMPUTE(TT, WH, WL) { \
    f32x16 ah = zero16(), ax = zero16(); \
    _Pragma("unroll") for (int ks = 0; ks < 5; ++ks) { \
        ah = __builtin_amdgcn_mfma_f32_32x32x16_f16(WH[ks], Hh[ks], ah, 0, 0, 0); \
        ax = __builtin_amdgcn_mfma_f32_32x32x16_f16(WL[ks], Hh[ks], ax, 0, 0, 0); \
        ax = __builtin_amdgcn_mfma_f32_32x32x16_f16(WH[ks], Hl[ks], ax, 0, 0, 0); } \
    float ph = 0.0f, px = 0.0f; \
    _Pragma("unroll") for (int r = 0; r < 16; ++r) { \
        ph = fmaf(ah[r], xsr[r], ph); px = fmaf(ax[r], xsr[r], px); } \
    float p = fmaf(px, 9.765625e-4f, ph); \
    p += __shfl_xor(p, 32); \
    p4[(TT) & 3] = p; \
    if (((TT) & 3) == 3 && l < 32) \
        *reinterpret_cast<float4*>(msgS + (size_t)rk * 32 + hf * 16 + ((TT) - 3)) = p4; }

    half8 WhA[5], WlA[5], WhB[5], WlB[5];
    LOADW(0, WhA, WlA)
#pragma unroll
    for (int g = 0; g < 8; ++g) {
        LOADW(2 * g + 1, WhB, WlB)
        COMPUTE(2 * g, WhA, WlA)
        if (g < 7) LOADW(2 * g + 2, WhA, WlA)
        COMPUTE(2 * g + 1, WhB, WlB)
    }
#undef LOADW
#undef COMPUTE
}

// ---------------- node update: x' = gelu(x@lw + lb + csr_mean(msgS)) ----------------
__global__ __launch_bounds__(256) void node_update_kernel(
    const float* __restrict__ xa, const float* __restrict__ xb,
    float* __restrict__ xout, const float* __restrict__ msgS,
    const int* __restrict__ off,
    const float* __restrict__ lw, const float* __restrict__ lb)
{
    __shared__ float lwS[1024];
#pragma unroll
    for (int c = 0; c < 4; ++c) lwS[threadIdx.x + 256 * c] = lw[threadIdx.x + 256 * c];
    __syncthreads();

    const int g = blockIdx.x * 256 + threadIdx.x;
    const int n = g >> 2;
    const int q = g & 3;

    const int b = off[n], e = off[n + 1];
    float sum[8];
#pragma unroll
    for (int oo = 0; oo < 8; ++oo) sum[oo] = 0.0f;
    for (int j = b; j < e; ++j) {
        const float4 m0 = *reinterpret_cast<const float4*>(msgS + (size_t)j * 32 + q * 8);
        const float4 m1 = *reinterpret_cast<const float4*>(msgS + (size_t)j * 32 + q * 8 + 4);
        sum[0] += m0.x; sum[1] += m0.y; sum[2] += m0.z; sum[3] += m0.w;
        sum[4] += m1.x; sum[5] += m1.y; sum[6] += m1.z; sum[7] += m1.w;
    }
    const float inv = (e > b) ? 1.0f / (float)(e - b) : 0.0f;
    float acc[8];
#pragma unroll
    for (int oo = 0; oo < 8; ++oo) acc[oo] = fmaf(sum[oo], inv, lb[q * 8 + oo]);

    float row[32];
#pragma unroll
    for (int i = 0; i < 32; i += 4) {
        float4 v = *reinterpret_cast<const float4*>(xa + (size_t)n * 32 + i);
        if (xb) {
            float4 u = *reinterpret_cast<const float4*>(xb + (size_t)n * 32 + i);
            v.x += u.x; v.y += u.y; v.z += u.z; v.w += u.w;
        }
        row[i + 0] = v.x; row[i + 1] = v.y; row[i + 2] = v.z; row[i + 3] = v.w;
    }
#pragma unroll
    for (int i = 0; i < 32; ++i) {
        const float xi = row[i];
#pragma unroll
        for (int oo = 0; oo < 8; ++oo) acc[oo] = fmaf(xi, lwS[i * 32 + q * 8 + oo], acc[oo]);
    }
    float4 o0, o1;
    o0.x = gelu_f(acc[0]); o0.y = gelu_f(acc[1]); o0.z = gelu_f(acc[2]); o0.w = gelu_f(acc[3]);
    o1.x = gelu_f(acc[4]); o1.y = gelu_f(acc[5]); o1.z = gelu_f(acc[6]); o1.w = gelu_f(acc[7]);
    *reinterpret_cast<float4*>(xout + (size_t)n * 32 + q * 8) = o0;
    *reinterpret_cast<float4*>(xout + (size_t)n * 32 + q * 8 + 4) = o1;
}

// ---------------- decoder ----------------
__global__ __launch_bounds__(256) void decode_kernel(
    const float* __restrict__ a, const float* __restrict__ b,
    const float* __restrict__ w1, const float* __restrict__ b1,
    const float* __restrict__ w2, const float* __restrict__ b2,
    float* __restrict__ out)
{
    const int n = blockIdx.x * 256 + threadIdx.x;
    float s[32];
#pragma unroll
    for (int i = 0; i < 32; ++i) s[i] = a[(size_t)n * 32 + i] + b[(size_t)n * 32 + i];
    float acc = b2[0];
#pragma unroll
    for (int j = 0; j < 16; ++j) {
        float h = b1[j];
#pragma unroll
        for (int i = 0; i < 32; ++i) h = fmaf(s[i], w1[i * 16 + j], h);
        acc = fmaf(gelu_f(h), w2[j], acc);
    }
    out[n] = acc;
}

extern "C" void kernel_launch(void* const* d_in, const int* in_sizes, int n_in,
                              void* d_out, int out_size, void* d_ws, size_t ws_size,
                              hipStream_t stream)
{
    const float* nodes = (const float*)d_in[0];
    const float* grid2 = (const float*)d_in[1];
    const int* ei[7];
    const float* ea[7];
    for (int s = 0; s < 7; ++s) {
        ei[s] = (const int*)d_in[2 + s];
        ea[s] = (const float*)d_in[9 + s];
    }
    const float* pw1 = (const float*)d_in[18];
    const float* pb1 = (const float*)d_in[19];
    const float* pw2 = (const float*)d_in[20];
    const float* pb2 = (const float*)d_in[21];
    const float* dw1 = (const float*)d_in[22];
    const float* db1 = (const float*)d_in[23];
    const float* dw2 = (const float*)d_in[24];
    const float* db2 = (const float*)d_in[25];
    const float* kw1 = (const float*)d_in[26];
    const float* kb1 = (const float*)d_in[27];
    const float* kw2 = (const float*)d_in[28];
    const float* kb2 = (const float*)d_in[29];
    const float* lw  = (const float*)d_in[30];
    const float* lb  = (const float*)d_in[31];

    float* ws  = (float*)d_ws;
    float* x0   = ws + 0 * (size_t)NL;
    float* n11  = ws + 1 * (size_t)NL;
    float* n12  = ws + 2 * (size_t)NL;
    float* n22  = ws + 3 * (size_t)NL;
    float* n23  = ws + 4 * (size_t)NL;
    float* n33  = ws + 5 * (size_t)NL;
    float* n32  = ws + 6 * (size_t)NL;
    float* n21  = ws + 7 * (size_t)NL;
    float* msgS = ws + 8 * (size_t)NL;                       // Ee*32 floats (4 MB)
    size_t cur = 8 * (size_t)NL + (size_t)Ee * 32;
    hf16* Wpack = (hf16*)(ws + cur);                         // 14*32*10*512 halves
    cur += (size_t)14 * 32 * 10 * 512 / 2;
    int* deg_i  = (int*)(ws + cur); cur += (size_t)7 * Nn;
    int* cursor = (int*)(ws + cur); cur += (size_t)7 * Nn;
    int* off    = (int*)(ws + cur); cur += (size_t)7 * (Nn + 1);
    int* rank   = (int*)(ws + cur);

    proj_kernel<<<Nn / 256, 256, 0, stream>>>(nodes, grid2, pw1, pb1, pw2, pb2,
                                              x0, deg_i, cursor);

    EPtrs ep;
    for (int s = 0; s < 7; ++s) ep.p[s] = ei[s];
    count_deg_kernel<<<7 * Ee / 256, 256, 0, stream>>>(ep, deg_i);
    scan_kernel<<<7, 256, 0, stream>>>(deg_i, off);
    rank_kernel<<<7 * Ee / 256, 256, 0, stream>>>(ep, off, cursor, rank);
    wprep_kernel<<<14 * 32, 320, 0, stream>>>(kw2, kb2, Wpack);

    auto layer = [&](int i, int d, int s, const float* xa, const float* xb, float* xo) {
        const int id = i * 2 + d;
        gemm_kernel<<<(Ee / 128) * 2, 256, 0, stream>>>(
            xa, xb, ei[s], rank + (size_t)s * Ee, ea[s],
            kw1 + (size_t)id * 320, kb1 + (size_t)id * 64,
            Wpack + (size_t)id * 32 * 5120, msgS);
        node_update_kernel<<<Nn * 4 / 256, 256, 0, stream>>>(
            xa, xb, xo, msgS, off + (size_t)s * (Nn + 1),
            lw + (size_t)id * 1024, lb + (size_t)id * 32);
    };
    auto gno_block = [&](int i, int s, const float* xa, const float* xb, float* xo) {
        layer(i, 0, s, xa, xb, xo);
        layer(i, 1, s, xo, nullptr, xo);
    };

    // block param index order: n11->0, n12->3, n22->1, n23->4, n33->2, n32->5, n21->6
    gno_block(0, 0, x0,  nullptr, n11);
    gno_block(3, 1, x0,  nullptr, n12);
    gno_block(1, 2, n12, nullptr, n22);
    gno_block(4, 3, n12, nullptr, n23);
    gno_block(2, 4, n23, nullptr, n33);
    gno_block(5, 5, n33, nullptr, n32);
    gno_block(6, 6, n32, n22,     n21);

    decode_kernel<<<Nn / 256, 256, 0, stream>>>(n11, n21, dw1, db1, dw2, db2, (float*)d_out);
}